// Round 2
// baseline (1655.604 us; speedup 1.0000x reference)
//
#include <hip/hip_runtime.h>
#include <math.h>

#define BB 128      // batch
#define TT 20       // time steps
#define EE 512      // embed dim
#define HH 512      // hidden dim
#define VV 10000    // vocab
#define G4 2048     // 4*H

typedef __attribute__((ext_vector_type(8))) short     bf16x8;
typedef __attribute__((ext_vector_type(4))) float     f32x4;
typedef __attribute__((ext_vector_type(8))) unsigned short u16x8;

static __device__ __forceinline__ unsigned short f2bf(float f) {
    union { float f; unsigned u; } v; v.f = f;
    const unsigned u = v.u;
    return (unsigned short)((u + 0x7FFFu + ((u >> 16) & 1u)) >> 16);  // RNE
}

// ---------------------------------------------------------------------------
// fp32 -> bf16 bulk convert (n multiple of 8)
// ---------------------------------------------------------------------------
__global__ __launch_bounds__(256) void cvt_bf16(
    const float* __restrict__ in, unsigned short* __restrict__ out, int n)
{
    const int i = (blockIdx.x * 256 + threadIdx.x) * 8;
    if (i >= n) return;
    const float4 a = *(const float4*)(in + i);
    const float4 b = *(const float4*)(in + i + 4);
    u16x8 o;
    o[0] = f2bf(a.x); o[1] = f2bf(a.y); o[2] = f2bf(a.z); o[3] = f2bf(a.w);
    o[4] = f2bf(b.x); o[5] = f2bf(b.y); o[6] = f2bf(b.z); o[7] = f2bf(b.w);
    *(u16x8*)(out + i) = o;
}

// ---------------------------------------------------------------------------
// gather inputs to bf16: X16[t*B+b] = t==0 ? features[b] : embed_w[captions[b][t-1]]
// ---------------------------------------------------------------------------
__global__ __launch_bounds__(128) void gather_x16(
    const float* __restrict__ features,
    const int* __restrict__ captions,
    const float* __restrict__ embed_w,
    unsigned short* __restrict__ X16)
{
    const int r = blockIdx.x;          // t*128 + b
    const int t = r >> 7;
    const int b = r & 127;
    const float* src;
    if (t == 0) src = features + (size_t)b * EE;
    else        src = embed_w + (size_t)captions[b * TT + (t - 1)] * EE;
    const float4 v = ((const float4*)src)[threadIdx.x];
    ushort4 o;
    o.x = f2bf(v.x); o.y = f2bf(v.y); o.z = f2bf(v.z); o.w = f2bf(v.w);
    ((ushort4*)(X16 + (size_t)r * EE))[threadIdx.x] = o;
}

// ---------------------------------------------------------------------------
// bf16 MFMA NT GEMM: C[M,N] = A[M,512] @ Bm[N,512]^T + bias0(+bias1)
// 128x128 tile, BK=32, 256 threads = 4 waves (2x2 of 64x64), fp32 out.
// LDS rows padded to 40 bf16 (80 B) -> frag ds_read_b128 bank-uniform.
// ---------------------------------------------------------------------------
__global__ __launch_bounds__(256) void gemm_bf16_mfma(
    const unsigned short* __restrict__ A,    // [M][512] bf16
    const unsigned short* __restrict__ Bm,   // [N][512] bf16
    const float* __restrict__ bias0,         // [N] or null
    const float* __restrict__ bias1,         // [N] or null
    float* __restrict__ C,                   // [M][N] fp32
    int M, int N)
{
    __shared__ unsigned short As[128][40];
    __shared__ unsigned short Bs[128][40];

    const int m0  = blockIdx.y * 128;
    const int n0  = blockIdx.x * 128;
    const int tid = threadIdx.x;
    const int wave = tid >> 6;
    const int lane = tid & 63;
    const int wr = wave >> 1, wc = wave & 1;     // wave quadrant (64x64)
    const int l15 = lane & 15, l4 = lane >> 4;

    f32x4 acc[4][4] = {};

    const int srow = tid >> 2;            // 0..63 (two passes -> 128 rows)
    const int sch  = (tid & 3) * 8;       // element offset 0,8,16,24

    for (int k0 = 0; k0 < 512; k0 += 32) {
        #pragma unroll
        for (int p = 0; p < 2; ++p) {
            const int r = srow + p * 64;
            {   // A tile (M rows always valid: M % 128 == 0)
                const uint4 v = *(const uint4*)(A + (size_t)(m0 + r) * 512 + k0 + sch);
                *(uint4*)&As[r][sch] = v;
            }
            {   // B tile with N guard
                const int nrow = n0 + r;
                uint4 v = make_uint4(0u, 0u, 0u, 0u);
                if (nrow < N)
                    v = *(const uint4*)(Bm + (size_t)nrow * 512 + k0 + sch);
                *(uint4*)&Bs[r][sch] = v;
            }
        }
        __syncthreads();

        bf16x8 af[4], bfr[4];
        #pragma unroll
        for (int i = 0; i < 4; ++i)
            af[i] = *(const bf16x8*)&As[wr * 64 + i * 16 + l15][l4 * 8];
        #pragma unroll
        for (int i = 0; i < 4; ++i)
            bfr[i] = *(const bf16x8*)&Bs[wc * 64 + i * 16 + l15][l4 * 8];

        #pragma unroll
        for (int i = 0; i < 4; ++i)
            #pragma unroll
            for (int j = 0; j < 4; ++j)
                acc[i][j] = __builtin_amdgcn_mfma_f32_16x16x32_bf16(
                    af[i], bfr[j], acc[i][j], 0, 0, 0);
        __syncthreads();
    }

    // epilogue: C/D layout col = lane&15, row = (lane>>4)*4 + reg
    #pragma unroll
    for (int j = 0; j < 4; ++j) {
        const int col = n0 + wc * 64 + j * 16 + l15;
        if (col >= N) continue;
        float bv = 0.f;
        if (bias0) bv += bias0[col];
        if (bias1) bv += bias1[col];
        #pragma unroll
        for (int i = 0; i < 4; ++i) {
            const int row = m0 + wr * 64 + i * 16 + l4 * 4;
            #pragma unroll
            for (int r = 0; r < 4; ++r)
                C[(size_t)(row + r) * N + col] = acc[i][j][r] + bv;
        }
    }
}

// ---------------------------------------------------------------------------
// barrier counters init
// ---------------------------------------------------------------------------
__global__ void init_bar(int* __restrict__ bar) {
    if (threadIdx.x < 8 * TT) bar[threadIdx.x] = 0;
}

// ---------------------------------------------------------------------------
// Fused persistent LSTM: 20 steps in one kernel.
// Grid 256 blocks (8 batch-groups x 32 n-tiles), 256 threads.
// Block covers b in [bt*16, bt*16+16), n in [nt*16, nt*16+16), all 4 gates.
// Thread (tr,tc): b = b0+tr, n = n0+tc; c stays in a register across steps.
// Per-group (32-block) software barrier: fresh counter per (group, step),
// agent-scope release/acquire atomics (cross-XCD safe); all 256 blocks
// co-resident (grid <= 256 CUs) so spinning cannot deadlock.
// ---------------------------------------------------------------------------
__global__ __launch_bounds__(256) void lstm_fused(
    const float* __restrict__ h0,     // [128][512]
    const float* __restrict__ c0,     // [128][512]
    const float* __restrict__ Xp,     // [2560][2048] fp32 (x-projection + biases)
    const float* __restrict__ W_hh,   // [2048][512] fp32
    float* __restrict__ Hb,           // [2560][512] fp32
    unsigned short* __restrict__ Hb16,// [2560][512] bf16
    int* __restrict__ bar)            // [8][TT]
{
    __shared__ float hs[16][512];     // hprev rows for this batch-group (32 KB)

    const int blk = blockIdx.x;
    const int bt = blk >> 5;          // 0..7 batch group
    const int nt = blk & 31;          // 0..31 n tile
    const int b0 = bt * 16;
    const int n0 = nt * 16;
    const int tid = threadIdx.x;
    const int tr = tid >> 4;          // 0..15 -> b
    const int tc = tid & 15;          // 0..15 -> n
    const int b = b0 + tr;
    const int n = n0 + tc;

    const float* w0 = W_hh + (size_t)(0 * 512 + n) * 512;
    const float* w1 = W_hh + (size_t)(1 * 512 + n) * 512;
    const float* w2 = W_hh + (size_t)(2 * 512 + n) * 512;
    const float* w3 = W_hh + (size_t)(3 * 512 + n) * 512;

    float creg = c0[(size_t)b * 512 + n];

    for (int t = 0; t < TT; ++t) {
        // stage hprev rows b0..b0+15 (coalesced float4)
        const float* hp = (t == 0) ? (h0 + (size_t)b0 * 512)
                                   : (Hb + ((size_t)(t - 1) * BB + b0) * 512);
        #pragma unroll
        for (int j = 0; j < 8; ++j) {
            const int idx = tid + j * 256;            // float4 index, 0..2047
            ((float4*)&hs[0][0])[idx] = ((const float4*)hp)[idx];
        }
        __syncthreads();

        float a0 = 0.f, a1 = 0.f, a2 = 0.f, a3 = 0.f;
        #pragma unroll 4
        for (int k = 0; k < 512; k += 4) {
            const float4 hv = *(const float4*)&hs[tr][k];
            const float4 wi = *(const float4*)(w0 + k);
            const float4 wf = *(const float4*)(w1 + k);
            const float4 wg = *(const float4*)(w2 + k);
            const float4 wo = *(const float4*)(w3 + k);
            a0 += hv.x * wi.x + hv.y * wi.y + hv.z * wi.z + hv.w * wi.w;
            a1 += hv.x * wf.x + hv.y * wf.y + hv.z * wf.z + hv.w * wf.w;
            a2 += hv.x * wg.x + hv.y * wg.y + hv.z * wg.z + hv.w * wg.w;
            a3 += hv.x * wo.x + hv.y * wo.y + hv.z * wo.z + hv.w * wo.w;
        }

        const size_t gr = (size_t)t * BB + b;
        const float* xr = Xp + gr * G4;
        const float gi = a0 + xr[0 * 512 + n];
        const float gf = a1 + xr[1 * 512 + n];
        const float gg = a2 + xr[2 * 512 + n];
        const float go = a3 + xr[3 * 512 + n];
        const float iv = 1.f / (1.f + expf(-gi));
        const float fv = 1.f / (1.f + expf(-gf));
        const float gv = tanhf(gg);
        const float ov = 1.f / (1.f + expf(-go));
        creg = fv * creg + iv * gv;
        const float hval = ov * tanhf(creg);
        Hb[gr * 512 + n] = hval;
        Hb16[gr * 512 + n] = f2bf(hval);

        // group barrier: all 32 n-tile blocks of this batch group
        __syncthreads();
        if (tid == 0) {
            int* slot = bar + bt * TT + t;
            __hip_atomic_fetch_add(slot, 1, __ATOMIC_RELEASE, __HIP_MEMORY_SCOPE_AGENT);
            while (__hip_atomic_load(slot, __ATOMIC_ACQUIRE, __HIP_MEMORY_SCOPE_AGENT) < 32)
                __builtin_amdgcn_s_sleep(2);
        }
        __syncthreads();
    }
}

// ---------------------------------------------------------------------------
extern "C" void kernel_launch(void* const* d_in, const int* in_sizes, int n_in,
                              void* d_out, int out_size, void* d_ws, size_t ws_size,
                              hipStream_t stream)
{
    const float* features = (const float*)d_in[0];
    const int*   captions = (const int*)d_in[1];
    const float* h0       = (const float*)d_in[2];
    const float* c0       = (const float*)d_in[3];
    const float* embed_w  = (const float*)d_in[4];
    const float* W_ih     = (const float*)d_in[5];
    const float* W_hh     = (const float*)d_in[6];
    const float* b_ih     = (const float*)d_in[7];
    const float* b_hh     = (const float*)d_in[8];
    const float* W_lin    = (const float*)d_in[9];
    const float* b_lin    = (const float*)d_in[10];
    float* out = (float*)d_out;

    // workspace layout (16B-aligned chunks)
    char* p = (char*)d_ws;
    unsigned short* X16    = (unsigned short*)p; p += (size_t)2560 * 512 * 2;   // 2.62 MB
    unsigned short* Wih16  = (unsigned short*)p; p += (size_t)2048 * 512 * 2;   // 2.10 MB
    unsigned short* Wlin16 = (unsigned short*)p; p += (size_t)10000 * 512 * 2;  // 10.24 MB
    unsigned short* Hb16   = (unsigned short*)p; p += (size_t)2560 * 512 * 2;   // 2.62 MB
    float*          Xp     = (float*)p;          p += (size_t)2560 * 2048 * 4;  // 20.97 MB
    float*          Hb     = (float*)p;          p += (size_t)2560 * 512 * 4;   // 5.24 MB
    int*            bar    = (int*)p;            p += 8 * TT * 4;

    // 1) weight converts + input gather (bf16)
    cvt_bf16<<<dim3((2048 * 512) / (256 * 8)), dim3(256), 0, stream>>>(W_ih, Wih16, 2048 * 512);
    cvt_bf16<<<dim3((10000 * 512) / (256 * 8)), dim3(256), 0, stream>>>(W_lin, Wlin16, 10000 * 512);
    gather_x16<<<dim3(TT * BB), dim3(128), 0, stream>>>(features, captions, embed_w, X16);

    // 2) input projection: Xp = X @ W_ih^T + b_ih + b_hh   (MFMA bf16)
    gemm_bf16_mfma<<<dim3(G4 / 128, (TT * BB) / 128), dim3(256), 0, stream>>>(
        X16, Wih16, b_ih, b_hh, Xp, TT * BB, G4);

    // 3) fused sequential LSTM (single persistent kernel, fp32 recurrence)
    init_bar<<<dim3(1), dim3(256), 0, stream>>>(bar);
    lstm_fused<<<dim3(256), dim3(256), 0, stream>>>(h0, c0, Xp, W_hh, Hb, Hb16, bar);

    // 4) output projection: out = H @ W_lin^T + b_lin   (MFMA bf16)
    gemm_bf16_mfma<<<dim3((VV + 127) / 128, (TT * BB) / 128), dim3(256), 0, stream>>>(
        Hb16, Wlin16, b_lin, nullptr, out, TT * BB, VV);
}

// Round 6
// 664.906 us; speedup vs baseline: 2.4900x; 2.4900x over previous
//
#include <hip/hip_runtime.h>
#include <math.h>

#define BB 128      // batch
#define TT 20       // time steps
#define EE 512      // embed dim
#define HH 512      // hidden dim
#define VV 10000    // vocab
#define G4 2048     // 4*H
#define NBLK 64     // lstm grid size

typedef __attribute__((ext_vector_type(8))) short     bf16x8;
typedef __attribute__((ext_vector_type(4))) float     f32x4;
typedef __attribute__((ext_vector_type(8))) unsigned short u16x8;

static __device__ __forceinline__ unsigned short f2bf(float f) {
    union { float f; unsigned u; } v; v.f = f;
    const unsigned u = v.u;
    return (unsigned short)((u + 0x7FFFu + ((u >> 16) & 1u)) >> 16);  // RNE
}
static __device__ __forceinline__ float bf2f(unsigned short h) {
    union { unsigned u; float f; } v; v.u = ((unsigned)h) << 16;
    return v.f;
}

// ---------------------------------------------------------------------------
// fp32 -> bf16 bulk convert (n multiple of 2048)
// ---------------------------------------------------------------------------
__global__ __launch_bounds__(256) void cvt_bf16(
    const float* __restrict__ in, unsigned short* __restrict__ out, int n)
{
    const int i = (blockIdx.x * 256 + threadIdx.x) * 8;
    if (i >= n) return;
    const float4 a = *(const float4*)(in + i);
    const float4 b = *(const float4*)(in + i + 4);
    u16x8 o;
    o[0] = f2bf(a.x); o[1] = f2bf(a.y); o[2] = f2bf(a.z); o[3] = f2bf(a.w);
    o[4] = f2bf(b.x); o[5] = f2bf(b.y); o[6] = f2bf(b.z); o[7] = f2bf(b.w);
    *(u16x8*)(out + i) = o;
}

// ---------------------------------------------------------------------------
// fp32 -> bf16 hi + bf16 lo (compensated split)
// ---------------------------------------------------------------------------
__global__ __launch_bounds__(256) void cvt_bf16_hilo(
    const float* __restrict__ in,
    unsigned short* __restrict__ hi, unsigned short* __restrict__ lo, int n)
{
    const int i = (blockIdx.x * 256 + threadIdx.x) * 8;
    if (i >= n) return;
    u16x8 oh, ol;
    #pragma unroll
    for (int j = 0; j < 8; ++j) {
        const float x = in[i + j];
        const unsigned short h = f2bf(x);
        oh[j] = h;
        ol[j] = f2bf(x - bf2f(h));
    }
    *(u16x8*)(hi + i) = oh;
    *(u16x8*)(lo + i) = ol;
}

// ---------------------------------------------------------------------------
// gather inputs to bf16: X16[t*B+b] = t==0 ? features[b] : embed_w[captions[b][t-1]]
// ---------------------------------------------------------------------------
__global__ __launch_bounds__(128) void gather_x16(
    const float* __restrict__ features,
    const int* __restrict__ captions,
    const float* __restrict__ embed_w,
    unsigned short* __restrict__ X16)
{
    const int r = blockIdx.x;          // t*128 + b
    const int t = r >> 7;
    const int b = r & 127;
    const float* src;
    if (t == 0) src = features + (size_t)b * EE;
    else        src = embed_w + (size_t)captions[b * TT + (t - 1)] * EE;
    const float4 v = ((const float4*)src)[threadIdx.x];
    ushort4 o;
    o.x = f2bf(v.x); o.y = f2bf(v.y); o.z = f2bf(v.z); o.w = f2bf(v.w);
    ((ushort4*)(X16 + (size_t)r * EE))[threadIdx.x] = o;
}

// ---------------------------------------------------------------------------
// bf16 MFMA NT GEMM: C[M,N] = A[M,512] @ Bm[N,512]^T + bias0(+bias1)
// 128x128 tile, BK=32, 256 threads = 4 waves (2x2 of 64x64), fp32 out.
// ---------------------------------------------------------------------------
__global__ __launch_bounds__(256) void gemm_bf16_mfma(
    const unsigned short* __restrict__ A,    // [M][512] bf16
    const unsigned short* __restrict__ Bm,   // [N][512] bf16
    const float* __restrict__ bias0,         // [N] or null
    const float* __restrict__ bias1,         // [N] or null
    float* __restrict__ C,                   // [M][N] fp32
    int M, int N)
{
    __shared__ unsigned short As[128][40];
    __shared__ unsigned short Bs[128][40];

    const int m0  = blockIdx.y * 128;
    const int n0  = blockIdx.x * 128;
    const int tid = threadIdx.x;
    const int wave = tid >> 6;
    const int lane = tid & 63;
    const int wr = wave >> 1, wc = wave & 1;     // wave quadrant (64x64)
    const int l15 = lane & 15, l4 = lane >> 4;

    f32x4 acc[4][4] = {};

    const int srow = tid >> 2;            // 0..63 (two passes -> 128 rows)
    const int sch  = (tid & 3) * 8;       // element offset 0,8,16,24

    for (int k0 = 0; k0 < 512; k0 += 32) {
        #pragma unroll
        for (int p = 0; p < 2; ++p) {
            const int r = srow + p * 64;
            {
                const uint4 v = *(const uint4*)(A + (size_t)(m0 + r) * 512 + k0 + sch);
                *(uint4*)&As[r][sch] = v;
            }
            {
                const int nrow = n0 + r;
                uint4 v = make_uint4(0u, 0u, 0u, 0u);
                if (nrow < N)
                    v = *(const uint4*)(Bm + (size_t)nrow * 512 + k0 + sch);
                *(uint4*)&Bs[r][sch] = v;
            }
        }
        __syncthreads();

        bf16x8 af[4], bfr[4];
        #pragma unroll
        for (int i = 0; i < 4; ++i)
            af[i] = *(const bf16x8*)&As[wr * 64 + i * 16 + l15][l4 * 8];
        #pragma unroll
        for (int i = 0; i < 4; ++i)
            bfr[i] = *(const bf16x8*)&Bs[wc * 64 + i * 16 + l15][l4 * 8];

        #pragma unroll
        for (int i = 0; i < 4; ++i)
            #pragma unroll
            for (int j = 0; j < 4; ++j)
                acc[i][j] = __builtin_amdgcn_mfma_f32_16x16x32_bf16(
                    af[i], bfr[j], acc[i][j], 0, 0, 0);
        __syncthreads();
    }

    #pragma unroll
    for (int j = 0; j < 4; ++j) {
        const int col = n0 + wc * 64 + j * 16 + l15;
        if (col >= N) continue;
        float bv = 0.f;
        if (bias0) bv += bias0[col];
        if (bias1) bv += bias1[col];
        #pragma unroll
        for (int i = 0; i < 4; ++i) {
            const int row = m0 + wr * 64 + i * 16 + l4 * 4;
            #pragma unroll
            for (int r = 0; r < 4; ++r)
                C[(size_t)(row + r) * N + col] = acc[i][j][r] + bv;
        }
    }
}

// ---------------------------------------------------------------------------
__global__ void init_bar(int* __restrict__ bar) {
    if (threadIdx.x < 32) bar[threadIdx.x] = 0;
}

// ---------------------------------------------------------------------------
// Persistent fused LSTM, W_hh resident in registers as MFMA fragments.
// Grid: 64 blocks = 2 m-halves x 32 h-col tiles. Block: 4 waves; wave g owns
// gate g's W-slice (16 cols x 512 k) as bf16 hi/lo fragments (128 VGPR).
// Per step: load h frags (bf16 hi/lo), 192 MFMAs, gate exchange via LDS,
// fp32 c-update in regs, store h bf16 hi/lo, grid barrier.
// h_t lives at Hhi/Hlo rows (t+1)*128.. ; rows 0..127 = h0.
// ---------------------------------------------------------------------------
__global__ __launch_bounds__(256, 1) void lstm_fused_mfma(
    const float* __restrict__ c0,          // [128][512]
    const float* __restrict__ Xp,          // [2560][2048] fp32
    const unsigned short* __restrict__ Whi,// [2048][512] bf16
    const unsigned short* __restrict__ Wlo,// [2048][512] bf16
    unsigned short* __restrict__ Hhi,      // [(TT+1)*128][512]
    unsigned short* __restrict__ Hlo,      // [(TT+1)*128][512]
    int* __restrict__ bar)                 // [32]
{
    __shared__ float gsh[4][64][17];       // [gate][m][n] padded

    const int blk   = blockIdx.x;
    const int mhalf = blk >> 5;            // 0,1
    const int n0    = (blk & 31) * 16;     // h-col tile
    const int tid   = threadIdx.x;
    const int wave  = tid >> 6;            // = gate index
    const int lane  = tid & 63;
    const int l15   = lane & 15, l4 = lane >> 4;

    // --- persistent W fragments (lane l: row n0+l15 of gate `wave`, k = kk*32+l4*8)
    bf16x8 whi[16], wlo[16];
    {
        const size_t wrow = (size_t)(wave * 512 + n0 + l15) * 512;
        #pragma unroll
        for (int kk = 0; kk < 16; ++kk) {
            whi[kk] = *(const bf16x8*)(Whi + wrow + kk * 32 + l4 * 8);
            wlo[kk] = *(const bf16x8*)(Wlo + wrow + kk * 32 + l4 * 8);
        }
    }

    // --- persistent c registers: thread -> col n0+(tid&15), rows (tid>>4)*4+{0..3}
    const int arow = (tid >> 4) * 4;       // 0..60 (local m)
    const int acol = tid & 15;
    float creg[4];
    #pragma unroll
    for (int j = 0; j < 4; ++j)
        creg[j] = c0[(size_t)(mhalf * 64 + arow + j) * 512 + n0 + acol];

    for (int t = 0; t < TT; ++t) {
        // --- recurrent MFMA: gates_g[m 0..63][n0..n0+15] for this wave's gate
        const size_t abase = ((size_t)t * 128 + mhalf * 64) * 512;
        f32x4 acc[4] = {};
        #pragma unroll
        for (int kk = 0; kk < 16; ++kk) {
            #pragma unroll
            for (int mi = 0; mi < 4; ++mi) {
                const size_t off = abase + (size_t)(mi * 16 + l15) * 512 + kk * 32 + l4 * 8;
                const bf16x8 ah = *(const bf16x8*)(Hhi + off);
                const bf16x8 al = *(const bf16x8*)(Hlo + off);
                acc[mi] = __builtin_amdgcn_mfma_f32_16x16x32_bf16(ah, whi[kk], acc[mi], 0, 0, 0);
                acc[mi] = __builtin_amdgcn_mfma_f32_16x16x32_bf16(al, whi[kk], acc[mi], 0, 0, 0);
                acc[mi] = __builtin_amdgcn_mfma_f32_16x16x32_bf16(ah, wlo[kk], acc[mi], 0, 0, 0);
            }
        }

        // --- gate exchange (C/D layout: row = mi*16 + l4*4 + r, col = l15)
        #pragma unroll
        for (int mi = 0; mi < 4; ++mi)
            #pragma unroll
            for (int r = 0; r < 4; ++r)
                gsh[wave][mi * 16 + l4 * 4 + r][l15] = acc[mi][r];
        __syncthreads();

        // --- activations + c/h update (4 rows per thread)
        #pragma unroll
        for (int j = 0; j < 4; ++j) {
            const int row = arow + j;                       // local m
            const size_t xrow = ((size_t)t * 128 + mhalf * 64 + row) * (size_t)G4;
            const int n = n0 + acol;
            const float gi = gsh[0][row][acol] + Xp[xrow + 0 * 512 + n];
            const float gf = gsh[1][row][acol] + Xp[xrow + 1 * 512 + n];
            const float gg = gsh[2][row][acol] + Xp[xrow + 2 * 512 + n];
            const float go = gsh[3][row][acol] + Xp[xrow + 3 * 512 + n];
            const float iv = 1.f / (1.f + expf(-gi));
            const float fv = 1.f / (1.f + expf(-gf));
            const float gv = tanhf(gg);
            const float ov = 1.f / (1.f + expf(-go));
            creg[j] = fv * creg[j] + iv * gv;
            const float hv = ov * tanhf(creg[j]);
            const unsigned short hh = f2bf(hv);
            const unsigned short hl = f2bf(hv - bf2f(hh));
            const size_t ho = ((size_t)(t + 1) * 128 + mhalf * 64 + row) * 512 + n;
            Hhi[ho] = hh;
            Hlo[ho] = hl;
        }

        // --- grid barrier (fresh counter per step; all 64 blocks co-resident)
        __syncthreads();
        if (tid == 0) {
            int* slot = bar + t;
            __hip_atomic_fetch_add(slot, 1, __ATOMIC_RELEASE, __HIP_MEMORY_SCOPE_AGENT);
            while (__hip_atomic_load(slot, __ATOMIC_RELAXED, __HIP_MEMORY_SCOPE_AGENT) < NBLK)
                __builtin_amdgcn_s_sleep(2);
            (void)__hip_atomic_load(slot, __ATOMIC_ACQUIRE, __HIP_MEMORY_SCOPE_AGENT);
        }
        __syncthreads();
    }
}

// ---------------------------------------------------------------------------
extern "C" void kernel_launch(void* const* d_in, const int* in_sizes, int n_in,
                              void* d_out, int out_size, void* d_ws, size_t ws_size,
                              hipStream_t stream)
{
    const float* features = (const float*)d_in[0];
    const int*   captions = (const int*)d_in[1];
    const float* h0       = (const float*)d_in[2];
    const float* c0       = (const float*)d_in[3];
    const float* embed_w  = (const float*)d_in[4];
    const float* W_ih     = (const float*)d_in[5];
    const float* W_hh     = (const float*)d_in[6];
    const float* b_ih     = (const float*)d_in[7];
    const float* b_hh     = (const float*)d_in[8];
    const float* W_lin    = (const float*)d_in[9];
    const float* b_lin    = (const float*)d_in[10];
    float* out = (float*)d_out;

    // workspace layout
    char* p = (char*)d_ws;
    unsigned short* X16    = (unsigned short*)p; p += (size_t)2560 * 512 * 2;        // 2.62 MB
    unsigned short* Wih16  = (unsigned short*)p; p += (size_t)2048 * 512 * 2;        // 2.10 MB
    unsigned short* Wlin16 = (unsigned short*)p; p += (size_t)10000 * 512 * 2;       // 10.24 MB
    unsigned short* WhhHi  = (unsigned short*)p; p += (size_t)2048 * 512 * 2;        // 2.10 MB
    unsigned short* WhhLo  = (unsigned short*)p; p += (size_t)2048 * 512 * 2;        // 2.10 MB
    unsigned short* Hhi    = (unsigned short*)p; p += (size_t)(TT + 1) * 128 * 512 * 2; // 2.75 MB
    unsigned short* Hlo    = (unsigned short*)p; p += (size_t)(TT + 1) * 128 * 512 * 2; // 2.75 MB
    float*          Xp     = (float*)p;          p += (size_t)2560 * 2048 * 4;       // 20.97 MB
    int*            bar    = (int*)p;            p += 128;

    // 1) converts + gather
    cvt_bf16<<<dim3(512),  dim3(256), 0, stream>>>(W_ih, Wih16, 2048 * 512);
    cvt_bf16<<<dim3(2500), dim3(256), 0, stream>>>(W_lin, Wlin16, 10000 * 512);
    cvt_bf16_hilo<<<dim3(512), dim3(256), 0, stream>>>(W_hh, WhhHi, WhhLo, 2048 * 512);
    cvt_bf16_hilo<<<dim3(32),  dim3(256), 0, stream>>>(h0, Hhi, Hlo, 128 * 512);
    gather_x16<<<dim3(TT * BB), dim3(128), 0, stream>>>(features, captions, embed_w, X16);

    // 2) input projection: Xp = X @ W_ih^T + b_ih + b_hh   (MFMA bf16)
    gemm_bf16_mfma<<<dim3(G4 / 128, (TT * BB) / 128), dim3(256), 0, stream>>>(
        X16, Wih16, b_ih, b_hh, Xp, TT * BB, G4);

    // 3) fused sequential LSTM (register-resident W_hh, compensated bf16)
    init_bar<<<dim3(1), dim3(256), 0, stream>>>(bar);
    lstm_fused_mfma<<<dim3(NBLK), dim3(256), 0, stream>>>(
        c0, Xp, WhhHi, WhhLo, Hhi, Hlo, bar);

    // 4) output projection: out = H @ W_lin^T + b_lin   (MFMA bf16)
    gemm_bf16_mfma<<<dim3((VV + 127) / 128, (TT * BB) / 128), dim3(256), 0, stream>>>(
        Hhi + (size_t)128 * 512, Wlin16, b_lin, nullptr, out, TT * BB, VV);
}

// Round 7
// 452.810 us; speedup vs baseline: 3.6563x; 1.4684x over previous
//
#include <hip/hip_runtime.h>
#include <math.h>

#define BB 128      // batch
#define TT 20       // time steps
#define EE 512      // embed dim
#define HH 512      // hidden dim
#define VV 10000    // vocab
#define G4 2048     // 4*H
#define NBLK 64     // lstm grid size (2 mhalf x 32 n-tiles)

typedef __attribute__((ext_vector_type(8))) short     bf16x8;
typedef __attribute__((ext_vector_type(4))) float     f32x4;
typedef __attribute__((ext_vector_type(8))) unsigned short u16x8;

static __device__ __forceinline__ unsigned short f2bf(float f) {
    union { float f; unsigned u; } v; v.f = f;
    const unsigned u = v.u;
    return (unsigned short)((u + 0x7FFFu + ((u >> 16) & 1u)) >> 16);  // RNE
}
static __device__ __forceinline__ float bf2f(unsigned short h) {
    union { unsigned u; float f; } v; v.u = ((unsigned)h) << 16;
    return v.f;
}

// ---------------------------------------------------------------------------
// fp32 -> bf16 bulk convert
// ---------------------------------------------------------------------------
__global__ __launch_bounds__(256) void cvt_bf16(
    const float* __restrict__ in, unsigned short* __restrict__ out, int n)
{
    const int i = (blockIdx.x * 256 + threadIdx.x) * 8;
    if (i >= n) return;
    const float4 a = *(const float4*)(in + i);
    const float4 b = *(const float4*)(in + i + 4);
    u16x8 o;
    o[0] = f2bf(a.x); o[1] = f2bf(a.y); o[2] = f2bf(a.z); o[3] = f2bf(a.w);
    o[4] = f2bf(b.x); o[5] = f2bf(b.y); o[6] = f2bf(b.z); o[7] = f2bf(b.w);
    *(u16x8*)(out + i) = o;
}

// ---------------------------------------------------------------------------
// fp32 -> bf16 hi + bf16 lo (compensated split)
// ---------------------------------------------------------------------------
__global__ __launch_bounds__(256) void cvt_bf16_hilo(
    const float* __restrict__ in,
    unsigned short* __restrict__ hi, unsigned short* __restrict__ lo, int n)
{
    const int i = (blockIdx.x * 256 + threadIdx.x) * 8;
    if (i >= n) return;
    u16x8 oh, ol;
    #pragma unroll
    for (int j = 0; j < 8; ++j) {
        const float x = in[i + j];
        const unsigned short h = f2bf(x);
        oh[j] = h;
        ol[j] = f2bf(x - bf2f(h));
    }
    *(u16x8*)(hi + i) = oh;
    *(u16x8*)(lo + i) = ol;
}

// ---------------------------------------------------------------------------
// gather inputs to bf16
// ---------------------------------------------------------------------------
__global__ __launch_bounds__(128) void gather_x16(
    const float* __restrict__ features,
    const int* __restrict__ captions,
    const float* __restrict__ embed_w,
    unsigned short* __restrict__ X16)
{
    const int r = blockIdx.x;          // t*128 + b
    const int t = r >> 7;
    const int b = r & 127;
    const float* src;
    if (t == 0) src = features + (size_t)b * EE;
    else        src = embed_w + (size_t)captions[b * TT + (t - 1)] * EE;
    const float4 v = ((const float4*)src)[threadIdx.x];
    ushort4 o;
    o.x = f2bf(v.x); o.y = f2bf(v.y); o.z = f2bf(v.z); o.w = f2bf(v.w);
    ((ushort4*)(X16 + (size_t)r * EE))[threadIdx.x] = o;
}

// ---------------------------------------------------------------------------
// bf16 MFMA NT GEMM (unchanged from R6 — measured working)
// ---------------------------------------------------------------------------
__global__ __launch_bounds__(256) void gemm_bf16_mfma(
    const unsigned short* __restrict__ A,    // [M][512] bf16
    const unsigned short* __restrict__ Bm,   // [N][512] bf16
    const float* __restrict__ bias0,         // [N] or null
    const float* __restrict__ bias1,         // [N] or null
    float* __restrict__ C,                   // [M][N] fp32
    int M, int N)
{
    __shared__ unsigned short As[128][40];
    __shared__ unsigned short Bs[128][40];

    const int m0  = blockIdx.y * 128;
    const int n0  = blockIdx.x * 128;
    const int tid = threadIdx.x;
    const int wave = tid >> 6;
    const int lane = tid & 63;
    const int wr = wave >> 1, wc = wave & 1;
    const int l15 = lane & 15, l4 = lane >> 4;

    f32x4 acc[4][4] = {};

    const int srow = tid >> 2;
    const int sch  = (tid & 3) * 8;

    for (int k0 = 0; k0 < 512; k0 += 32) {
        #pragma unroll
        for (int p = 0; p < 2; ++p) {
            const int r = srow + p * 64;
            {
                const uint4 v = *(const uint4*)(A + (size_t)(m0 + r) * 512 + k0 + sch);
                *(uint4*)&As[r][sch] = v;
            }
            {
                const int nrow = n0 + r;
                uint4 v = make_uint4(0u, 0u, 0u, 0u);
                if (nrow < N)
                    v = *(const uint4*)(Bm + (size_t)nrow * 512 + k0 + sch);
                *(uint4*)&Bs[r][sch] = v;
            }
        }
        __syncthreads();

        bf16x8 af[4], bfr[4];
        #pragma unroll
        for (int i = 0; i < 4; ++i)
            af[i] = *(const bf16x8*)&As[wr * 64 + i * 16 + l15][l4 * 8];
        #pragma unroll
        for (int i = 0; i < 4; ++i)
            bfr[i] = *(const bf16x8*)&Bs[wc * 64 + i * 16 + l15][l4 * 8];

        #pragma unroll
        for (int i = 0; i < 4; ++i)
            #pragma unroll
            for (int j = 0; j < 4; ++j)
                acc[i][j] = __builtin_amdgcn_mfma_f32_16x16x32_bf16(
                    af[i], bfr[j], acc[i][j], 0, 0, 0);
        __syncthreads();
    }

    #pragma unroll
    for (int j = 0; j < 4; ++j) {
        const int col = n0 + wc * 64 + j * 16 + l15;
        if (col >= N) continue;
        float bv = 0.f;
        if (bias0) bv += bias0[col];
        if (bias1) bv += bias1[col];
        #pragma unroll
        for (int i = 0; i < 4; ++i) {
            const int row = m0 + wr * 64 + i * 16 + l4 * 4;
            #pragma unroll
            for (int r = 0; r < 4; ++r)
                C[(size_t)(row + r) * N + col] = acc[i][j][r] + bv;
        }
    }
}

// ---------------------------------------------------------------------------
__global__ void init_bar(int* __restrict__ bar) {
    if (threadIdx.x < 2 * TT) bar[threadIdx.x] = 0;
}

// ---------------------------------------------------------------------------
// Persistent fused LSTM v2.
// Grid 64 blocks = 2 independent m-half groups x 32 n-tiles. 512 threads =
// 8 waves (2 waves/SIMD). Wave w: gate = w&3, row-half mh2 = w>>2 (32 rows).
// W_hh slice (16 cols x 512 k, bf16 hi+lo) register-resident (128 VGPR/lane).
// Per step: h staged cooperatively into double-buffered LDS (8 chunks of
// 64 k, one coalesced 16B load/thread/array/chunk), 96 MFMAs/wave from LDS,
// gate exchange via LDS, fp32 c-update (f32x4, tid<256), vectorized Xp read
// + h hi/lo store, per-mhalf 32-block barrier (skipped at t=TT-1).
// ---------------------------------------------------------------------------
__global__ __launch_bounds__(512, 1) void lstm_fused_mfma2(
    const float* __restrict__ c0,          // [128][512]
    const float* __restrict__ Xp,          // [2560][2048] fp32
    const unsigned short* __restrict__ Whi,// [2048][512] bf16
    const unsigned short* __restrict__ Wlo,// [2048][512] bf16
    unsigned short* __restrict__ Hhi,      // [(TT+1)*128][512]
    unsigned short* __restrict__ Hlo,      // [(TT+1)*128][512]
    int* __restrict__ bar)                 // [2][TT]
{
    __shared__ unsigned short hsH[2][64][72];  // 72 = 64 + 8 pad (2-way banks)
    __shared__ unsigned short hsL[2][64][72];
    __shared__ float gsh[4][64][17];

    const int blk   = blockIdx.x;
    const int mhalf = blk >> 5;            // 0,1 (independent groups)
    const int n0    = (blk & 31) * 16;     // h-col tile
    const int tid   = threadIdx.x;
    const int w     = tid >> 6;
    const int lane  = tid & 63;
    const int l15   = lane & 15, l4 = lane >> 4;
    const int gate  = w & 3;
    const int mh2   = w >> 2;              // 0/1 -> rows mh2*32..+31

    // --- persistent W fragments: gate's cols n0+l15, k = kk*32 + l4*8
    bf16x8 whi[16], wlo[16];
    {
        const size_t wrow = (size_t)(gate * 512 + n0 + l15) * 512;
        #pragma unroll
        for (int kk = 0; kk < 16; ++kk) {
            whi[kk] = *(const bf16x8*)(Whi + wrow + kk * 32 + l4 * 8);
            wlo[kk] = *(const bf16x8*)(Wlo + wrow + kk * 32 + l4 * 8);
        }
    }

    // --- staging ids: 1x 16B per array per chunk
    const int srow = tid >> 3;            // 0..63
    const int sseg = (tid & 7) * 8;       // element offset 0..56

    // --- activation ids (tid<256): row 0..63, 4 consecutive n
    const int arow = tid >> 2;
    const int aq   = (tid & 3) * 4;

    f32x4 creg = {};
    if (tid < 256)
        creg = *(const f32x4*)(c0 + (size_t)(mhalf * 64 + arow) * 512 + n0 + aq);

    for (int t = 0; t < TT; ++t) {
        const size_t abase = ((size_t)t * 128 + mhalf * 64) * 512;
        const size_t srcrow = abase + (size_t)srow * 512;

        // chunk 0 stage
        {
            const uint4 rh = *(const uint4*)(Hhi + srcrow + sseg);
            const uint4 rl = *(const uint4*)(Hlo + srcrow + sseg);
            *(uint4*)&hsH[0][srow][sseg] = rh;
            *(uint4*)&hsL[0][srow][sseg] = rl;
        }

        f32x4 acc[2] = {};
        #pragma unroll
        for (int c = 0; c < 8; ++c) {
            __syncthreads();                       // buf(c&1) ready
            uint4 nh = {}, nl = {};
            if (c < 7) {                           // issue next-chunk loads
                nh = *(const uint4*)(Hhi + srcrow + (c + 1) * 64 + sseg);
                nl = *(const uint4*)(Hlo + srcrow + (c + 1) * 64 + sseg);
            }
            const int buf = c & 1;
            #pragma unroll
            for (int kkl = 0; kkl < 2; ++kkl) {
                const int kkg = c * 2 + kkl;
                #pragma unroll
                for (int mi = 0; mi < 2; ++mi) {
                    const int r = mh2 * 32 + mi * 16 + l15;
                    const bf16x8 ah = *(const bf16x8*)&hsH[buf][r][kkl * 32 + l4 * 8];
                    const bf16x8 al = *(const bf16x8*)&hsL[buf][r][kkl * 32 + l4 * 8];
                    acc[mi] = __builtin_amdgcn_mfma_f32_16x16x32_bf16(ah, whi[kkg], acc[mi], 0, 0, 0);
                    acc[mi] = __builtin_amdgcn_mfma_f32_16x16x32_bf16(al, whi[kkg], acc[mi], 0, 0, 0);
                    acc[mi] = __builtin_amdgcn_mfma_f32_16x16x32_bf16(ah, wlo[kkg], acc[mi], 0, 0, 0);
                }
            }
            if (c < 7) {                           // write next buf (race-free:
                *(uint4*)&hsH[buf ^ 1][srow][sseg] = nh;   // sync above separates
                *(uint4*)&hsL[buf ^ 1][srow][sseg] = nl;   // from c-1's readers)
            }
        }

        // --- gate exchange (C/D: row = mi*16 + l4*4 + r, col = l15)
        #pragma unroll
        for (int mi = 0; mi < 2; ++mi)
            #pragma unroll
            for (int r = 0; r < 4; ++r)
                gsh[gate][mh2 * 32 + mi * 16 + l4 * 4 + r][l15] = acc[mi][r];
        __syncthreads();

        // --- activations + c/h update (tid<256: one f32x4 each)
        if (tid < 256) {
            const size_t xrow = ((size_t)t * 128 + mhalf * 64 + arow) * (size_t)G4;
            const float4 xi = *(const float4*)(Xp + xrow + 0 * 512 + n0 + aq);
            const float4 xf = *(const float4*)(Xp + xrow + 1 * 512 + n0 + aq);
            const float4 xg = *(const float4*)(Xp + xrow + 2 * 512 + n0 + aq);
            const float4 xo = *(const float4*)(Xp + xrow + 3 * 512 + n0 + aq);
            const float gxi[4] = {xi.x, xi.y, xi.z, xi.w};
            const float gxf[4] = {xf.x, xf.y, xf.z, xf.w};
            const float gxg[4] = {xg.x, xg.y, xg.z, xg.w};
            const float gxo[4] = {xo.x, xo.y, xo.z, xo.w};
            ushort4 hh4, hl4;
            unsigned short* ph = (unsigned short*)&hh4;
            unsigned short* pl = (unsigned short*)&hl4;
            #pragma unroll
            for (int j = 0; j < 4; ++j) {
                const float gi = gsh[0][arow][aq + j] + gxi[j];
                const float gf = gsh[1][arow][aq + j] + gxf[j];
                const float gg = gsh[2][arow][aq + j] + gxg[j];
                const float go = gsh[3][arow][aq + j] + gxo[j];
                const float iv = 1.f / (1.f + expf(-gi));
                const float fv = 1.f / (1.f + expf(-gf));
                const float gv = tanhf(gg);
                const float ov = 1.f / (1.f + expf(-go));
                creg[j] = fv * creg[j] + iv * gv;
                const float hv = ov * tanhf(creg[j]);
                const unsigned short h16 = f2bf(hv);
                ph[j] = h16;
                pl[j] = f2bf(hv - bf2f(h16));
            }
            const size_t ho = ((size_t)(t + 1) * 128 + mhalf * 64 + arow) * 512 + n0 + aq;
            *(ushort4*)(Hhi + ho) = hh4;
            *(ushort4*)(Hlo + ho) = hl4;
        }

        // --- per-mhalf group barrier (32 blocks); not needed after last step
        __syncthreads();
        if (t < TT - 1) {
            if (tid == 0) {
                int* slot = bar + mhalf * TT + t;
                __hip_atomic_fetch_add(slot, 1, __ATOMIC_RELEASE, __HIP_MEMORY_SCOPE_AGENT);
                while (__hip_atomic_load(slot, __ATOMIC_RELAXED, __HIP_MEMORY_SCOPE_AGENT) < 32)
                    __builtin_amdgcn_s_sleep(2);
                (void)__hip_atomic_load(slot, __ATOMIC_ACQUIRE, __HIP_MEMORY_SCOPE_AGENT);
            }
            __syncthreads();
        }
    }
}

// ---------------------------------------------------------------------------
extern "C" void kernel_launch(void* const* d_in, const int* in_sizes, int n_in,
                              void* d_out, int out_size, void* d_ws, size_t ws_size,
                              hipStream_t stream)
{
    const float* features = (const float*)d_in[0];
    const int*   captions = (const int*)d_in[1];
    const float* h0       = (const float*)d_in[2];
    const float* c0       = (const float*)d_in[3];
    const float* embed_w  = (const float*)d_in[4];
    const float* W_ih     = (const float*)d_in[5];
    const float* W_hh     = (const float*)d_in[6];
    const float* b_ih     = (const float*)d_in[7];
    const float* b_hh     = (const float*)d_in[8];
    const float* W_lin    = (const float*)d_in[9];
    const float* b_lin    = (const float*)d_in[10];
    float* out = (float*)d_out;

    // workspace layout
    char* p = (char*)d_ws;
    unsigned short* X16    = (unsigned short*)p; p += (size_t)2560 * 512 * 2;
    unsigned short* Wih16  = (unsigned short*)p; p += (size_t)2048 * 512 * 2;
    unsigned short* Wlin16 = (unsigned short*)p; p += (size_t)10000 * 512 * 2;
    unsigned short* WhhHi  = (unsigned short*)p; p += (size_t)2048 * 512 * 2;
    unsigned short* WhhLo  = (unsigned short*)p; p += (size_t)2048 * 512 * 2;
    unsigned short* Hhi    = (unsigned short*)p; p += (size_t)(TT + 1) * 128 * 512 * 2;
    unsigned short* Hlo    = (unsigned short*)p; p += (size_t)(TT + 1) * 128 * 512 * 2;
    float*          Xp     = (float*)p;          p += (size_t)2560 * 2048 * 4;
    int*            bar    = (int*)p;            p += 256;

    // 1) converts + gather
    cvt_bf16<<<dim3(512),  dim3(256), 0, stream>>>(W_ih, Wih16, 2048 * 512);
    cvt_bf16<<<dim3(2500), dim3(256), 0, stream>>>(W_lin, Wlin16, 10000 * 512);
    cvt_bf16_hilo<<<dim3(512), dim3(256), 0, stream>>>(W_hh, WhhHi, WhhLo, 2048 * 512);
    cvt_bf16_hilo<<<dim3(32),  dim3(256), 0, stream>>>(h0, Hhi, Hlo, 128 * 512);
    gather_x16<<<dim3(TT * BB), dim3(128), 0, stream>>>(features, captions, embed_w, X16);

    // 2) input projection: Xp = X @ W_ih^T + b_ih + b_hh   (MFMA bf16)
    gemm_bf16_mfma<<<dim3(G4 / 128, (TT * BB) / 128), dim3(256), 0, stream>>>(
        X16, Wih16, b_ih, b_hh, Xp, TT * BB, G4);

    // 3) fused sequential LSTM v2
    init_bar<<<dim3(1), dim3(64), 0, stream>>>(bar);
    lstm_fused_mfma2<<<dim3(NBLK), dim3(512), 0, stream>>>(
        c0, Xp, WhhHi, WhhLo, Hhi, Hlo, bar);

    // 4) output projection: out = H @ W_lin^T + b_lin   (MFMA bf16)
    gemm_bf16_mfma<<<dim3((VV + 127) / 128, (TT * BB) / 128), dim3(256), 0, stream>>>(
        Hhi + (size_t)128 * 512, Wlin16, b_lin, nullptr, out, TT * BB, VV);
}

// Round 9
// 424.562 us; speedup vs baseline: 3.8996x; 1.0665x over previous
//
#include <hip/hip_runtime.h>
#include <math.h>

#define BB 128      // batch
#define TT 20       // time steps
#define EE 512      // embed dim
#define HH 512      // hidden dim
#define VV 10000    // vocab
#define G4 2048     // 4*H
#define NBLK 64     // lstm grid size (2 mhalf x 32 n-tiles)

typedef __attribute__((ext_vector_type(8))) short     bf16x8;
typedef __attribute__((ext_vector_type(4))) float     f32x4;
typedef __attribute__((ext_vector_type(8))) unsigned short u16x8;

static __device__ __forceinline__ unsigned short f2bf(float f) {
    union { float f; unsigned u; } v; v.f = f;
    const unsigned u = v.u;
    return (unsigned short)((u + 0x7FFFu + ((u >> 16) & 1u)) >> 16);  // RNE
}
static __device__ __forceinline__ float bf2f(unsigned short h) {
    union { unsigned u; float f; } v; v.u = ((unsigned)h) << 16;
    return v.f;
}
static __device__ __forceinline__ float sigm_fast(float x) {
    return 1.f / (1.f + __expf(-x));
}
static __device__ __forceinline__ float tanh_fast(float x) {
    const float ax = fabsf(x);
    const float e  = __expf(2.f * ax);
    const float t  = 1.f - 2.f / (e + 1.f);
    return copysignf(t, x);
}

// ---------------------------------------------------------------------------
// fp32 -> bf16 bulk convert
// ---------------------------------------------------------------------------
__global__ __launch_bounds__(256) void cvt_bf16(
    const float* __restrict__ in, unsigned short* __restrict__ out, int n)
{
    const int i = (blockIdx.x * 256 + threadIdx.x) * 8;
    if (i >= n) return;
    const float4 a = *(const float4*)(in + i);
    const float4 b = *(const float4*)(in + i + 4);
    u16x8 o;
    o[0] = f2bf(a.x); o[1] = f2bf(a.y); o[2] = f2bf(a.z); o[3] = f2bf(a.w);
    o[4] = f2bf(b.x); o[5] = f2bf(b.y); o[6] = f2bf(b.z); o[7] = f2bf(b.w);
    *(u16x8*)(out + i) = o;
}

// ---------------------------------------------------------------------------
// fp32 -> bf16 hi + bf16 lo (compensated split)
// ---------------------------------------------------------------------------
__global__ __launch_bounds__(256) void cvt_bf16_hilo(
    const float* __restrict__ in,
    unsigned short* __restrict__ hi, unsigned short* __restrict__ lo, int n)
{
    const int i = (blockIdx.x * 256 + threadIdx.x) * 8;
    if (i >= n) return;
    u16x8 oh, ol;
    #pragma unroll
    for (int j = 0; j < 8; ++j) {
        const float x = in[i + j];
        const unsigned short h = f2bf(x);
        oh[j] = h;
        ol[j] = f2bf(x - bf2f(h));
    }
    *(u16x8*)(hi + i) = oh;
    *(u16x8*)(lo + i) = ol;
}

// ---------------------------------------------------------------------------
// gather inputs to bf16
// ---------------------------------------------------------------------------
__global__ __launch_bounds__(128) void gather_x16(
    const float* __restrict__ features,
    const int* __restrict__ captions,
    const float* __restrict__ embed_w,
    unsigned short* __restrict__ X16)
{
    const int r = blockIdx.x;          // t*128 + b
    const int t = r >> 7;
    const int b = r & 127;
    const float* src;
    if (t == 0) src = features + (size_t)b * EE;
    else        src = embed_w + (size_t)captions[b * TT + (t - 1)] * EE;
    const float4 v = ((const float4*)src)[threadIdx.x];
    ushort4 o;
    o.x = f2bf(v.x); o.y = f2bf(v.y); o.z = f2bf(v.z); o.w = f2bf(v.w);
    ((ushort4*)(X16 + (size_t)r * EE))[threadIdx.x] = o;
}

// ---------------------------------------------------------------------------
// bf16 MFMA NT GEMM (unchanged — measured working)
// ---------------------------------------------------------------------------
__global__ __launch_bounds__(256) void gemm_bf16_mfma(
    const unsigned short* __restrict__ A,    // [M][512] bf16
    const unsigned short* __restrict__ Bm,   // [N][512] bf16
    const float* __restrict__ bias0,         // [N] or null
    const float* __restrict__ bias1,         // [N] or null
    float* __restrict__ C,                   // [M][N] fp32
    int M, int N)
{
    __shared__ unsigned short As[128][40];
    __shared__ unsigned short Bs[128][40];

    const int m0  = blockIdx.y * 128;
    const int n0  = blockIdx.x * 128;
    const int tid = threadIdx.x;
    const int wave = tid >> 6;
    const int lane = tid & 63;
    const int wr = wave >> 1, wc = wave & 1;
    const int l15 = lane & 15, l4 = lane >> 4;

    f32x4 acc[4][4] = {};

    const int srow = tid >> 2;
    const int sch  = (tid & 3) * 8;

    for (int k0 = 0; k0 < 512; k0 += 32) {
        #pragma unroll
        for (int p = 0; p < 2; ++p) {
            const int r = srow + p * 64;
            {
                const uint4 v = *(const uint4*)(A + (size_t)(m0 + r) * 512 + k0 + sch);
                *(uint4*)&As[r][sch] = v;
            }
            {
                const int nrow = n0 + r;
                uint4 v = make_uint4(0u, 0u, 0u, 0u);
                if (nrow < N)
                    v = *(const uint4*)(Bm + (size_t)nrow * 512 + k0 + sch);
                *(uint4*)&Bs[r][sch] = v;
            }
        }
        __syncthreads();

        bf16x8 af[4], bfr[4];
        #pragma unroll
        for (int i = 0; i < 4; ++i)
            af[i] = *(const bf16x8*)&As[wr * 64 + i * 16 + l15][l4 * 8];
        #pragma unroll
        for (int i = 0; i < 4; ++i)
            bfr[i] = *(const bf16x8*)&Bs[wc * 64 + i * 16 + l15][l4 * 8];

        #pragma unroll
        for (int i = 0; i < 4; ++i)
            #pragma unroll
            for (int j = 0; j < 4; ++j)
                acc[i][j] = __builtin_amdgcn_mfma_f32_16x16x32_bf16(
                    af[i], bfr[j], acc[i][j], 0, 0, 0);
        __syncthreads();
    }

    #pragma unroll
    for (int j = 0; j < 4; ++j) {
        const int col = n0 + wc * 64 + j * 16 + l15;
        if (col >= N) continue;
        float bv = 0.f;
        if (bias0) bv += bias0[col];
        if (bias1) bv += bias1[col];
        #pragma unroll
        for (int i = 0; i < 4; ++i) {
            const int row = m0 + wr * 64 + i * 16 + l4 * 4;
            #pragma unroll
            for (int r = 0; r < 4; ++r)
                C[(size_t)(row + r) * N + col] = acc[i][j][r] + bv;
        }
    }
}

// ---------------------------------------------------------------------------
__global__ __launch_bounds__(512) void init_flags(int* __restrict__ flags) {
    for (int i = threadIdx.x; i < 2 * TT * 32; i += 512) flags[i] = 0;
}

// ---------------------------------------------------------------------------
// Persistent fused LSTM v3 — flattened per-step critical path.
// Grid 64 = 2 independent m-half groups x 32 n-tiles; 512 threads = 8 waves.
// Wave w: gate = w&3, row-half mh2 = w>>2. W_hh (16 cols x 512 k, bf16 hi+lo)
// register-resident. Per step:
//   Xp prefetch -> single-shot h staging (XOR-swizzled LDS, 128 KiB) -> sync
//   -> 4 interleaved 24-deep MFMA chains -> sync -> gate exchange (gsh
//   aliases staging LDS) -> sync -> activation (fast exp/tanh) + h store
//   -> flag-array barrier (release store to own slot, wave-ballot poll).
// ---------------------------------------------------------------------------
#define HS_IDX(row, col) ((((row) << 9) + (col)) ^ (((row) & 7) << 3))

__global__ __launch_bounds__(512, 1) void lstm_fused_mfma3(
    const float* __restrict__ c0,          // [128][512]
    const float* __restrict__ Xp,          // [2560][2048] fp32
    const unsigned short* __restrict__ Whi,// [2048][512] bf16
    const unsigned short* __restrict__ Wlo,// [2048][512] bf16
    unsigned short* __restrict__ Hhi,      // [(TT+1)*128][512]
    unsigned short* __restrict__ Hlo,      // [(TT+1)*128][512]
    int* __restrict__ flags)               // [2][TT][32]
{
    __shared__ char smem[131072];          // hsH[64][512] ++ hsL[64][512], swizzled
    unsigned short* hsH = (unsigned short*)smem;
    unsigned short* hsL = hsH + 64 * 512;
    float* gsh = (float*)smem;             // [4][64][17] aliased (17408 B)

    const int blk   = blockIdx.x;
    const int mhalf = blk >> 5;            // independent groups
    const int ntile = blk & 31;
    const int n0    = ntile * 16;
    const int tid   = threadIdx.x;
    const int w     = tid >> 6;
    const int lane  = tid & 63;
    const int l15   = lane & 15, l4 = lane >> 4;
    const int gate  = w & 3;
    const int mh2   = w >> 2;

    // --- persistent W fragments: gate's cols n0+l15, k = kk*32 + l4*8
    bf16x8 whi[16], wlo[16];
    {
        const size_t wrow = (size_t)(gate * 512 + n0 + l15) * 512;
        #pragma unroll
        for (int kk = 0; kk < 16; ++kk) {
            whi[kk] = *(const bf16x8*)(Whi + wrow + kk * 32 + l4 * 8);
            wlo[kk] = *(const bf16x8*)(Wlo + wrow + kk * 32 + l4 * 8);
        }
    }

    // staging ids: 8 segs of 16B per array per thread
    const int srow  = tid >> 3;            // 0..63
    const int scol0 = (tid & 7) * 8;       // elem offset

    // activation ids (tid<256): row 0..63, 4 consecutive n
    const int arow = tid >> 2;
    const int aq   = (tid & 3) * 4;

    f32x4 creg = {};
    if (tid < 256)
        creg = *(const f32x4*)(c0 + (size_t)(mhalf * 64 + arow) * 512 + n0 + aq);

    for (int t = 0; t < TT; ++t) {
        const size_t abase = ((size_t)t * 128 + mhalf * 64) * 512;

        // --- Xp prefetch (hides under staging + MFMA)
        float4 xi, xf, xg, xo;
        if (tid < 256) {
            const size_t xrow = ((size_t)t * 128 + mhalf * 64 + arow) * (size_t)G4;
            xi = *(const float4*)(Xp + xrow + 0 * 512 + n0 + aq);
            xf = *(const float4*)(Xp + xrow + 1 * 512 + n0 + aq);
            xg = *(const float4*)(Xp + xrow + 2 * 512 + n0 + aq);
            xo = *(const float4*)(Xp + xrow + 3 * 512 + n0 + aq);
        }

        // --- single-shot staging: 16 loads + 16 LDS writes per thread
        {
            const unsigned short* gH = Hhi + abase + (size_t)srow * 512;
            const unsigned short* gL = Hlo + abase + (size_t)srow * 512;
            #pragma unroll
            for (int s = 0; s < 8; ++s) {
                const int col = scol0 + s * 64;
                const uint4 vh = *(const uint4*)(gH + col);
                const uint4 vl = *(const uint4*)(gL + col);
                *(uint4*)&hsH[HS_IDX(srow, col)] = vh;
                *(uint4*)&hsL[HS_IDX(srow, col)] = vl;
            }
        }
        __syncthreads();

        // --- MFMA: 4 interleaved chains (2 mi x 2 k-halves), 24 deep each
        f32x4 a0[2] = {}, a1[2] = {};
        #pragma unroll
        for (int kk = 0; kk < 8; ++kk) {
            #pragma unroll
            for (int mi = 0; mi < 2; ++mi) {
                const int r  = mh2 * 32 + mi * 16 + l15;
                const int cA = kk * 32 + l4 * 8;
                const int cB = (kk + 8) * 32 + l4 * 8;
                const bf16x8 ahA = *(const bf16x8*)&hsH[HS_IDX(r, cA)];
                const bf16x8 alA = *(const bf16x8*)&hsL[HS_IDX(r, cA)];
                const bf16x8 ahB = *(const bf16x8*)&hsH[HS_IDX(r, cB)];
                const bf16x8 alB = *(const bf16x8*)&hsL[HS_IDX(r, cB)];
                a0[mi] = __builtin_amdgcn_mfma_f32_16x16x32_bf16(ahA, whi[kk],     a0[mi], 0, 0, 0);
                a0[mi] = __builtin_amdgcn_mfma_f32_16x16x32_bf16(alA, whi[kk],     a0[mi], 0, 0, 0);
                a0[mi] = __builtin_amdgcn_mfma_f32_16x16x32_bf16(ahA, wlo[kk],     a0[mi], 0, 0, 0);
                a1[mi] = __builtin_amdgcn_mfma_f32_16x16x32_bf16(ahB, whi[kk + 8], a1[mi], 0, 0, 0);
                a1[mi] = __builtin_amdgcn_mfma_f32_16x16x32_bf16(alB, whi[kk + 8], a1[mi], 0, 0, 0);
                a1[mi] = __builtin_amdgcn_mfma_f32_16x16x32_bf16(ahB, wlo[kk + 8], a1[mi], 0, 0, 0);
            }
        }
        __syncthreads();   // all LDS reads done before gsh (aliased) is written

        // --- gate exchange (C/D: row = mi*16 + l4*4 + r, col = l15)
        #pragma unroll
        for (int mi = 0; mi < 2; ++mi) {
            const f32x4 acc = a0[mi] + a1[mi];
            #pragma unroll
            for (int r = 0; r < 4; ++r)
                gsh[gate * 1088 + (mh2 * 32 + mi * 16 + l4 * 4 + r) * 17 + l15] = acc[r];
        }
        __syncthreads();

        // --- activations + c/h update (tid<256: one f32x4 each)
        if (tid < 256) {
            const float gxi[4] = {xi.x, xi.y, xi.z, xi.w};
            const float gxf[4] = {xf.x, xf.y, xf.z, xf.w};
            const float gxg[4] = {xg.x, xg.y, xg.z, xg.w};
            const float gxo[4] = {xo.x, xo.y, xo.z, xo.w};
            ushort4 hh4, hl4;
            unsigned short* ph = (unsigned short*)&hh4;
            unsigned short* pl = (unsigned short*)&hl4;
            #pragma unroll
            for (int j = 0; j < 4; ++j) {
                const float gi = gsh[0 * 1088 + arow * 17 + aq + j] + gxi[j];
                const float gf = gsh[1 * 1088 + arow * 17 + aq + j] + gxf[j];
                const float gg = gsh[2 * 1088 + arow * 17 + aq + j] + gxg[j];
                const float go = gsh[3 * 1088 + arow * 17 + aq + j] + gxo[j];
                const float iv = sigm_fast(gi);
                const float fv = sigm_fast(gf);
                const float gv = tanh_fast(gg);
                const float ov = sigm_fast(go);
                creg[j] = fv * creg[j] + iv * gv;
                const float hv = ov * tanh_fast(creg[j]);
                const unsigned short h16 = f2bf(hv);
                ph[j] = h16;
                pl[j] = f2bf(hv - bf2f(h16));
            }
            const size_t ho = ((size_t)(t + 1) * 128 + mhalf * 64 + arow) * 512 + n0 + aq;
            *(ushort4*)(Hhi + ho) = hh4;
            *(ushort4*)(Hlo + ho) = hl4;
        }

        // --- flag-array group barrier (32 blocks per mhalf); skip after last
        if (t < TT - 1) {
            __syncthreads();               // drains all h stores (vmcnt 0)
            int* base = flags + (mhalf * TT + t) * 32;
            if (tid == 0)
                __hip_atomic_store(base + ntile, 1, __ATOMIC_RELEASE, __HIP_MEMORY_SCOPE_AGENT);
            if (tid < 64) {
                const int myf = lane & 31;
                while (true) {
                    const int v = __hip_atomic_load(base + myf, __ATOMIC_RELAXED, __HIP_MEMORY_SCOPE_AGENT);
                    if (__ballot(v != 0) == ~0ull) break;
                    __builtin_amdgcn_s_sleep(1);
                }
                if (lane == 0)
                    (void)__hip_atomic_load(base, __ATOMIC_ACQUIRE, __HIP_MEMORY_SCOPE_AGENT);
            }
            __syncthreads();
        }
    }
}

// ---------------------------------------------------------------------------
extern "C" void kernel_launch(void* const* d_in, const int* in_sizes, int n_in,
                              void* d_out, int out_size, void* d_ws, size_t ws_size,
                              hipStream_t stream)
{
    const float* features = (const float*)d_in[0];
    const int*   captions = (const int*)d_in[1];
    const float* h0       = (const float*)d_in[2];
    const float* c0       = (const float*)d_in[3];
    const float* embed_w  = (const float*)d_in[4];
    const float* W_ih     = (const float*)d_in[5];
    const float* W_hh     = (const float*)d_in[6];
    const float* b_ih     = (const float*)d_in[7];
    const float* b_hh     = (const float*)d_in[8];
    const float* W_lin    = (const float*)d_in[9];
    const float* b_lin    = (const float*)d_in[10];
    float* out = (float*)d_out;

    // workspace layout
    char* p = (char*)d_ws;
    unsigned short* X16    = (unsigned short*)p; p += (size_t)2560 * 512 * 2;
    unsigned short* Wih16  = (unsigned short*)p; p += (size_t)2048 * 512 * 2;
    unsigned short* Wlin16 = (unsigned short*)p; p += (size_t)10000 * 512 * 2;
    unsigned short* WhhHi  = (unsigned short*)p; p += (size_t)2048 * 512 * 2;
    unsigned short* WhhLo  = (unsigned short*)p; p += (size_t)2048 * 512 * 2;
    unsigned short* Hhi    = (unsigned short*)p; p += (size_t)(TT + 1) * 128 * 512 * 2;
    unsigned short* Hlo    = (unsigned short*)p; p += (size_t)(TT + 1) * 128 * 512 * 2;
    float*          Xp     = (float*)p;          p += (size_t)2560 * 2048 * 4;
    int*            flags  = (int*)p;            p += 2 * TT * 32 * 4;

    // 1) converts + gather
    cvt_bf16<<<dim3(512),  dim3(256), 0, stream>>>(W_ih, Wih16, 2048 * 512);
    cvt_bf16<<<dim3(2500), dim3(256), 0, stream>>>(W_lin, Wlin16, 10000 * 512);
    cvt_bf16_hilo<<<dim3(512), dim3(256), 0, stream>>>(W_hh, WhhHi, WhhLo, 2048 * 512);
    cvt_bf16_hilo<<<dim3(32),  dim3(256), 0, stream>>>(h0, Hhi, Hlo, 128 * 512);
    gather_x16<<<dim3(TT * BB), dim3(128), 0, stream>>>(features, captions, embed_w, X16);

    // 2) input projection: Xp = X @ W_ih^T + b_ih + b_hh   (MFMA bf16)
    gemm_bf16_mfma<<<dim3(G4 / 128, (TT * BB) / 128), dim3(256), 0, stream>>>(
        X16, Wih16, b_ih, b_hh, Xp, TT * BB, G4);

    // 3) fused sequential LSTM v3
    init_flags<<<dim3(1), dim3(512), 0, stream>>>(flags);
    lstm_fused_mfma3<<<dim3(NBLK), dim3(512), 0, stream>>>(
        c0, Xp, WhhHi, WhhLo, Hhi, Hlo, flags);

    // 4) output projection: out = H @ W_lin^T + b_lin   (MFMA bf16)
    gemm_bf16_mfma<<<dim3((VV + 127) / 128, (TT * BB) / 128), dim3(256), 0, stream>>>(
        Hhi + (size_t)128 * 512, Wlin16, b_lin, nullptr, out, TT * BB, VV);
}